// Round 3
// baseline (279.148 us; speedup 1.0000x reference)
//
#include <hip/hip_runtime.h>
#include <stdint.h>

// ---------- helpers ----------
typedef __attribute__((ext_vector_type(8))) short bf16x8;   // 8 bf16 in 4 VGPRs
typedef __attribute__((ext_vector_type(4))) float f32x4;

__device__ __forceinline__ float bflo(uint32_t v) { return __uint_as_float(v << 16); }
__device__ __forceinline__ float bfhi(uint32_t v) { return __uint_as_float(v & 0xffff0000u); }
__device__ __forceinline__ float bf2f(uint16_t h) { return __uint_as_float(((uint32_t)h) << 16); }
__device__ __forceinline__ uint16_t f2bf(float f) {  // RNE, finite inputs only
  uint32_t u = __float_as_uint(f);
  u += 0x7fffu + ((u >> 16) & 1u);
  return (uint16_t)(u >> 16);
}

// ---------- dtype detector ----------
// bf16-pair words: bits[14:8] = exponent[7:1] of the low element -> in
// [0x3A,0x41] for |x| in [2^-11, 16] (virtually always for N(0,1) data).
// f32 words: bits[14:8] are mantissa noise -> ~6% hit rate. 4096 words:
// bf16 ~ 4096 hits, f32 ~ 256 hits. flag: 0 = bf16, 1 = f32.
__global__ __launch_bounds__(64) void detect_k(const uint32_t* __restrict__ w,
                                               int* __restrict__ flag)
{
  int t = threadIdx.x;
  int cnt = 0;
  for (int i = 0; i < 64; i++) {
    uint32_t b = (w[t * 64 + i] >> 8) & 0x7F;
    cnt += (b >= 0x3A && b <= 0x41) ? 1 : 0;
  }
  for (int o = 32; o; o >>= 1) cnt += __shfl_xor(cnt, o);
  if (t == 0) *flag = (cnt > 2048) ? 0 : 1;
}

// ---------- prep: transpose weights -> bf16 Wt, biases/gamma/beta -> f32, zero BN accums ----------
template<int DT>   // DT: external dtype, 0=bf16 1=f32; runs iff *flag==DT
__global__ __launch_bounds__(256) void prep_k(
    const int* __restrict__ flag,
    const void* __restrict__ W1, const void* __restrict__ Wf1,
    const void* __restrict__ W2, const void* __restrict__ Wf2,
    const void* __restrict__ b1, const void* __restrict__ bf1,
    const void* __restrict__ b2, const void* __restrict__ bf2,
    const void* __restrict__ gam, const void* __restrict__ bet,
    uint16_t* __restrict__ T1, uint16_t* __restrict__ Tf1,
    uint16_t* __restrict__ T2, uint16_t* __restrict__ Tf2,
    float* __restrict__ fb, float* __restrict__ fgb, float* __restrict__ gz)
{
  if (*flag != DT) return;
  int t = blockIdx.x * 256 + threadIdx.x;   // 0..98303
  {
    const void* S; uint16_t* D; int Kw; int e;
    if (t < 16384)      { S = W1;  D = T1;  Kw = 128; e = t; }
    else if (t < 49152) { S = Wf1; D = Tf1; Kw = 256; e = t - 16384; }
    else if (t < 65536) { S = W2;  D = T2;  Kw = 128; e = t - 49152; }
    else                { S = Wf2; D = Tf2; Kw = 256; e = t - 65536; }
    int k = e >> 7, n = e & 127;
    uint16_t v = (DT == 0) ? ((const uint16_t*)S)[e] : f2bf(((const float*)S)[e]);
    D[n * Kw + k] = v;
  }
  if (blockIdx.x == 0) {
    int i = threadIdx.x;
    for (int j = i; j < 512; j += 256) {   // fb: [b1|bf1|b2|bf2]
      const void* src = (j < 128) ? b1 : (j < 256) ? bf1 : (j < 384) ? b2 : bf2;
      int e = j & 127;
      fb[j] = (DT == 0) ? bf2f(((const uint16_t*)src)[e]) : ((const float*)src)[e];
    }
    {                                      // fgb: [gamma|beta]
      const void* src = (i < 128) ? gam : bet;
      int e = i & 127;
      fgb[i] = (DT == 0) ? bf2f(((const uint16_t*)src)[e]) : ((const float*)src)[e];
    }
    gz[i] = 0.f;                           // g_sum[128]+g_sq[128]
  }
}

// ---------- GEMM: D[M,128] = act(A[M,K] @ W[K,128] + b) ----------
// A0 dtype ADT (0=bf16,1=f32); A1 (K==256 tail) always internal bf16.
// Output dtype ODT. GATE: -1 always run, else run iff *flag==GATE.
template<int K, int NT, bool RELU, bool STATS, int ADT, int ODT, int GATE>
__global__ __launch_bounds__(256) void gemm_k(
    const int* __restrict__ flag,
    const void* __restrict__ A0v, const uint16_t* __restrict__ A1,
    const uint16_t* __restrict__ Wt, const float* __restrict__ bias,
    void* __restrict__ Dv, float* __restrict__ g_sum, float* __restrict__ g_sq,
    int M)
{
  if (GATE >= 0 && *flag != GATE) return;

  constexpr int KT = K / 32;        // MFMA k-steps
  constexpr int NC = NT * 16;       // output cols per block
  __shared__ __align__(16) uint16_t lds[NC * K];   // 32 KB
  __shared__ float s_sum[NC], s_sq[NC];

  const int tid = threadIdx.x;
  const int n0 = blockIdx.y * NC;

  // stage Wt rows [n0, n0+NC), 16B chunks, chunk-xor swizzle
  for (int i = tid; i < NC * K / 8; i += 256) {
    int nl = i / (K / 8);
    int ci = i % (K / 8);
    int phys = ci ^ (nl & 7);
    bf16x8 v = *(const bf16x8*)(Wt + (size_t)(n0 + nl) * K + ci * 8);
    *(bf16x8*)(&lds[nl * K + phys * 8]) = v;
  }
  if (STATS && tid < NC) { s_sum[tid] = 0.f; s_sq[tid] = 0.f; }
  __syncthreads();

  const int lane = tid & 63;
  const int wave = tid >> 6;
  const int m    = lane & 15;
  const int quad = lane >> 4;
  const int row0 = blockIdx.x * 64 + wave * 16;

  if (row0 < M) {
    const int arow = row0 + m;
    bf16x8 afr[KT];
#pragma unroll
    for (int kk = 0; kk < KT; kk++) {
      if (K == 256 && kk >= 4) {
        afr[kk] = *(const bf16x8*)(A1 + (size_t)arow * 128 + (kk - 4) * 32 + quad * 8);
      } else if (ADT == 0) {
        afr[kk] = *(const bf16x8*)((const uint16_t*)A0v + (size_t)arow * 128 + kk * 32 + quad * 8);
      } else {
        const float* p = (const float*)A0v + (size_t)arow * 128 + kk * 32 + quad * 8;
        f32x4 f0 = *(const f32x4*)p;
        f32x4 f1 = *(const f32x4*)(p + 4);
        bf16x8 a;
        a[0] = (short)f2bf(f0[0]); a[1] = (short)f2bf(f0[1]);
        a[2] = (short)f2bf(f0[2]); a[3] = (short)f2bf(f0[3]);
        a[4] = (short)f2bf(f1[0]); a[5] = (short)f2bf(f1[1]);
        a[6] = (short)f2bf(f1[2]); a[7] = (short)f2bf(f1[3]);
        afr[kk] = a;
      }
    }
#pragma unroll
    for (int nt = 0; nt < NT; nt++) {
      f32x4 acc = {0.f, 0.f, 0.f, 0.f};
      const int browl = nt * 16 + m;
#pragma unroll
      for (int kk = 0; kk < KT; kk++) {
        int phys = (kk * 4 + quad) ^ (browl & 7);
        bf16x8 b = *(const bf16x8*)(&lds[browl * K + phys * 8]);
        acc = __builtin_amdgcn_mfma_f32_16x16x32_bf16(afr[kk], b, acc, 0, 0, 0);
      }
      const int col = n0 + nt * 16 + m;
      const float bv = bias[col];
      float vals[4];
#pragma unroll
      for (int r = 0; r < 4; r++) {
        float v = acc[r] + bv;
        if (RELU) v = fmaxf(v, 0.f);
        vals[r] = v;
        size_t oidx = (size_t)(row0 + quad * 4 + r) * 128 + col;
        if (ODT == 0) ((uint16_t*)Dv)[oidx] = f2bf(v);
        else          ((float*)Dv)[oidx] = v;
      }
      if (STATS) {
        float s = vals[0] + vals[1] + vals[2] + vals[3];
        float q = vals[0]*vals[0] + vals[1]*vals[1] + vals[2]*vals[2] + vals[3]*vals[3];
        s += __shfl_xor(s, 16); s += __shfl_xor(s, 32);
        q += __shfl_xor(q, 16); q += __shfl_xor(q, 32);
        if (quad == 0) {
          atomicAdd(&s_sum[nt * 16 + m], s);
          atomicAdd(&s_sq [nt * 16 + m], q);
        }
      }
    }
  }
  if (STATS) {
    __syncthreads();
    if (tid < NC) {
      atomicAdd(&g_sum[n0 + tid], s_sum[tid]);
      atomicAdd(&g_sq [n0 + tid], s_sq [tid]);
    }
  }
}

// ---------- gather + max over S neighbors (internal bf16, no gate) ----------
template<int S>
__global__ __launch_bounds__(256) void gather_k(
    const uint32_t* __restrict__ H, const int* __restrict__ idx,
    uint32_t* __restrict__ OUT, int M)
{
  const int lane = threadIdx.x & 63;
  int w = blockIdx.x * 4 + (threadIdx.x >> 6);
  const int nw = gridDim.x * 4;
  for (int r = w; r < M; r += nw) {
    const int* ir = idx + (size_t)r * S;
    float m0 = -3.4e38f, m1 = -3.4e38f;
#pragma unroll
    for (int s = 0; s < S; s++) {
      uint32_t j = (uint32_t)ir[s];
      if (j >= (uint32_t)M) j = 0;          // safety clamp
      uint32_t v = H[(size_t)j * 64 + lane];
      m0 = fmaxf(m0, bflo(v));
      m1 = fmaxf(m1, bfhi(v));
    }
    OUT[(size_t)r * 64 + lane] = (__float_as_uint(m1) & 0xffff0000u) | (__float_as_uint(m0) >> 16);
  }
}

// ---------- BN (batch stats) + row L2 normalize (internal bf16, no gate) ----------
__global__ __launch_bounds__(256) void bn_norm_k(
    const uint32_t* __restrict__ Y, const float* __restrict__ g_sum,
    const float* __restrict__ g_sq, const float* __restrict__ fgb,
    uint32_t* __restrict__ X, int M)
{
  __shared__ float sc[128], sh[128];
  const int tid = threadIdx.x;
  if (tid < 128) {
    float invN = 1.0f / (float)M;
    float mean = g_sum[tid] * invN;
    float var  = fmaxf(g_sq[tid] * invN - mean * mean, 0.f);
    float s = fgb[tid] * rsqrtf(var + 1e-5f);
    sc[tid] = s;
    sh[tid] = fgb[128 + tid] - mean * s;
  }
  __syncthreads();
  const int lane = tid & 63;
  const float s0 = sc[2*lane], s1 = sc[2*lane+1];
  const float h0 = sh[2*lane], h1 = sh[2*lane+1];
  int w = blockIdx.x * 4 + (tid >> 6);
  const int nw = gridDim.x * 4;
  for (int r = w; r < M; r += nw) {
    uint32_t v = Y[(size_t)r * 64 + lane];
    float x0 = bflo(v) * s0 + h0;
    float x1 = bfhi(v) * s1 + h1;
    float q = x0*x0 + x1*x1;
    q += __shfl_xor(q, 1);  q += __shfl_xor(q, 2);  q += __shfl_xor(q, 4);
    q += __shfl_xor(q, 8);  q += __shfl_xor(q, 16); q += __shfl_xor(q, 32);
    float inv = 1.0f / (sqrtf(q) + 1e-6f);
    x0 *= inv; x1 *= inv;
    X[(size_t)r * 64 + lane] = ((uint32_t)f2bf(x1) << 16) | (uint32_t)f2bf(x0);
  }
}

// ---------- launch ----------
extern "C" void kernel_launch(void* const* d_in, const int* in_sizes, int n_in,
                              void* d_out, int out_size, void* d_ws, size_t ws_size,
                              hipStream_t stream)
{
  const void* features = d_in[0];
  const int*  idx1     = (const int*)d_in[1];
  const int*  idx2     = (const int*)d_in[2];
  const void* agg1_W   = d_in[3];
  const void* agg1_b   = d_in[4];
  const void* fc1_W    = d_in[5];
  const void* fc1_b    = d_in[6];
  const void* agg2_W   = d_in[7];
  const void* agg2_b   = d_in[8];
  const void* fc2_W    = d_in[9];
  const void* fc2_b    = d_in[10];
  const void* bn_g     = d_in[11];
  const void* bn_b     = d_in[12];

  const int N = in_sizes[0] / 128;          // 50000 (multiple of 16)

  // workspace carve-up (16B-aligned); total ~25.8 MB
  char* w = (char*)d_ws;
  float* g_sum = (float*)w;  w += 512;
  float* g_sq  = (float*)w;  w += 512;
  int*   flag  = (int*)w;    w += 16;
  uint16_t* T1  = (uint16_t*)w; w += 128 * 128 * 2;
  uint16_t* Tf1 = (uint16_t*)w; w += 128 * 256 * 2;
  uint16_t* T2  = (uint16_t*)w; w += 128 * 128 * 2;
  uint16_t* Tf2 = (uint16_t*)w; w += 128 * 256 * 2;
  float* fb  = (float*)w; w += 512 * 4;     // [b1|bf1|b2|bf2] as f32
  float* fgb = (float*)w; w += 256 * 4;     // [gamma|beta] as f32
  size_t NB = (size_t)N * 128 * 2;
  uint16_t* bufA = (uint16_t*)w; w += NB;   // agg1 -> x
  uint16_t* bufB = (uint16_t*)w; w += NB;   // y -> agg2
  uint16_t* hbuf = (uint16_t*)d_out;        // h1 / h2 scratch lives in d_out

  detect_k<<<1, 64, 0, stream>>>((const uint32_t*)features, flag);
  prep_k<0><<<384, 256, 0, stream>>>(flag, agg1_W, fc1_W, agg2_W, fc2_W,
      agg1_b, fc1_b, agg2_b, fc2_b, bn_g, bn_b, T1, Tf1, T2, Tf2, fb, fgb, g_sum);
  prep_k<1><<<384, 256, 0, stream>>>(flag, agg1_W, fc1_W, agg2_W, fc2_W,
      agg1_b, fc1_b, agg2_b, fc2_b, bn_g, bn_b, T1, Tf1, T2, Tf2, fb, fgb, g_sum);

  const int rb = (N + 63) / 64;

  // h1 = relu(X @ W1 + b1) -> d_out scratch (internal bf16)
  gemm_k<128, 8, true, false, 0, 0, 0><<<dim3(rb, 1), 256, 0, stream>>>(
      flag, features, nullptr, T1, fb + 0, hbuf, nullptr, nullptr, N);
  gemm_k<128, 8, true, false, 1, 0, 1><<<dim3(rb, 1), 256, 0, stream>>>(
      flag, features, nullptr, T1, fb + 0, hbuf, nullptr, nullptr, N);
  // agg1 = max-gather(h1, idx1) -> bufA
  gather_k<25><<<1024, 256, 0, stream>>>((const uint32_t*)hbuf, idx1, (uint32_t*)bufA, N);
  // y = relu([X, agg1] @ fc1 + b) -> bufB, fused BN stats
  gemm_k<256, 4, true, true, 0, 0, 0><<<dim3(rb, 2), 256, 0, stream>>>(
      flag, features, bufA, Tf1, fb + 128, bufB, g_sum, g_sq, N);
  gemm_k<256, 4, true, true, 1, 0, 1><<<dim3(rb, 2), 256, 0, stream>>>(
      flag, features, bufA, Tf1, fb + 128, bufB, g_sum, g_sq, N);
  // x = L2normalize(BN(y)) -> bufA
  bn_norm_k<<<512, 256, 0, stream>>>((const uint32_t*)bufB, g_sum, g_sq, fgb,
                                     (uint32_t*)bufA, N);
  // h2 = relu(x @ W2 + b2) -> d_out scratch (all internal; ungated)
  gemm_k<128, 8, true, false, 0, 0, -1><<<dim3(rb, 1), 256, 0, stream>>>(
      flag, bufA, nullptr, T2, fb + 256, hbuf, nullptr, nullptr, N);
  // agg2 = max-gather(h2, idx2) -> bufB
  gather_k<25><<<1024, 256, 0, stream>>>((const uint32_t*)hbuf, idx2, (uint32_t*)bufB, N);
  // out = [x, agg2] @ fc2 + b -> d_out (output dtype per flag)
  gemm_k<256, 4, false, false, 0, 0, 0><<<dim3(rb, 2), 256, 0, stream>>>(
      flag, bufA, bufB, Tf2, fb + 384, d_out, nullptr, nullptr, N);
  gemm_k<256, 4, false, false, 0, 1, 1><<<dim3(rb, 2), 256, 0, stream>>>(
      flag, bufA, bufB, Tf2, fb + 384, d_out, nullptr, nullptr, N);

  (void)n_in; (void)out_size; (void)ws_size;
}

// Round 4
// 278.773 us; speedup vs baseline: 1.0013x; 1.0013x over previous
//
#include <hip/hip_runtime.h>
#include <stdint.h>

// ---------- helpers ----------
typedef __attribute__((ext_vector_type(8))) short bf16x8;   // 8 bf16 in 4 VGPRs
typedef __attribute__((ext_vector_type(4))) float f32x4;

__device__ __forceinline__ float bflo(uint32_t v) { return __uint_as_float(v << 16); }
__device__ __forceinline__ float bfhi(uint32_t v) { return __uint_as_float(v & 0xffff0000u); }
__device__ __forceinline__ uint16_t f2bf(float f) {  // RNE, finite inputs only
  uint32_t u = __float_as_uint(f);
  u += 0x7fffu + ((u >> 16) & 1u);
  return (uint16_t)(u >> 16);
}

#define NSHADOW 64   // BN-stats shadow copies (contention / 64)

// ---------- prep: transpose f32 weights -> bf16 Wt[128][K]; biases -> f32;
// zero the shadow accumulators. 384 blocks x 256 = 98304 threads = total W elems.
__global__ __launch_bounds__(256) void prep_k(
    const float* __restrict__ W1, const float* __restrict__ Wf1,
    const float* __restrict__ W2, const float* __restrict__ Wf2,
    const float* __restrict__ b1, const float* __restrict__ bf1,
    const float* __restrict__ b2, const float* __restrict__ bf2,
    const float* __restrict__ gam, const float* __restrict__ bet,
    uint16_t* __restrict__ T1, uint16_t* __restrict__ Tf1,
    uint16_t* __restrict__ T2, uint16_t* __restrict__ Tf2,
    float* __restrict__ fb, float* __restrict__ fgb,
    float* __restrict__ shadow)
{
  int t = blockIdx.x * 256 + threadIdx.x;   // 0..98303
  if (t < NSHADOW * 256) shadow[t] = 0.f;
  {
    const float* S; uint16_t* D; int Kw; int e;
    if (t < 16384)      { S = W1;  D = T1;  Kw = 128; e = t; }
    else if (t < 49152) { S = Wf1; D = Tf1; Kw = 256; e = t - 16384; }
    else if (t < 65536) { S = W2;  D = T2;  Kw = 128; e = t - 49152; }
    else                { S = Wf2; D = Tf2; Kw = 256; e = t - 65536; }
    int k = e >> 7, n = e & 127;
    D[n * Kw + k] = f2bf(S[e]);
  }
  if (blockIdx.x == 0) {
    int i = threadIdx.x;
    for (int j = i; j < 512; j += 256) {   // fb: [b1|bf1|b2|bf2]
      const float* src = (j < 128) ? b1 : (j < 256) ? bf1 : (j < 384) ? b2 : bf2;
      fb[j] = src[j & 127];
    }
    fgb[i] = (i < 128) ? gam[i] : bet[i & 127];   // [gamma|beta]
  }
}

// ---------- GEMM: D[M,128] = act(A[M,K] @ W[K,128] + b) ----------
// A0 dtype ADT (0=bf16,1=f32); A1 (K==256 upper half) always bf16.
// Block: 64 rows x 32 cols (NT=2), col-split via blockIdx.y (128/32 = 4).
// Wt tile staged in LDS in MFMA-fragment order: chunk (nt,kk,lane) at
// ((nt*KT+kk)*64+lane)*16B -> lane-sequential ds_read_b128, conflict-free.
template<int K, int NT, bool RELU, bool STATS, int ADT, int ODT>
__global__ __launch_bounds__(256) void gemm_k(
    const void* __restrict__ A0v, const uint16_t* __restrict__ A1,
    const uint16_t* __restrict__ Wt, const float* __restrict__ bias,
    void* __restrict__ Dv, float* __restrict__ shadow, int M)
{
  constexpr int KT = K / 32;        // MFMA k-steps
  constexpr int NC = NT * 16;       // output cols per block (32)
  constexpr int CH = K / 8;         // 16B chunks per col
  __shared__ __align__(16) uint16_t lds[NC * K];   // 16 KB (K=256) / 8 KB (K=128)
  __shared__ float s_sum[NC], s_sq[NC];

  const int tid = threadIdx.x;
  const int n0 = blockIdx.y * NC;

  // stage Wt cols [n0, n0+NC) -> fragment-ordered LDS (col-fastest iteration:
  // consecutive threads hit consecutive LDS lane slots -> conflict-free writes)
  for (int i = tid; i < NC * CH; i += 256) {
    int col = i % NC, k8 = i / NC;
    bf16x8 v = *(const bf16x8*)(Wt + (size_t)(n0 + col) * K + k8 * 8);
    int c = ((col >> 4) * KT + (k8 >> 2)) * 64 + (k8 & 3) * 16 + (col & 15);
    *(bf16x8*)(&lds[c * 8]) = v;
  }
  if (STATS && tid < NC) { s_sum[tid] = 0.f; s_sq[tid] = 0.f; }
  __syncthreads();

  const int lane = tid & 63;
  const int wave = tid >> 6;
  const int m    = lane & 15;
  const int quad = lane >> 4;
  const int row0 = blockIdx.x * 64 + wave * 16;   // M % 16 == 0

  if (row0 < M) {
    const int arow = row0 + m;
    bf16x8 afr[KT];
#pragma unroll
    for (int kk = 0; kk < KT; kk++) {
      if (K == 256 && kk >= 4) {
        afr[kk] = *(const bf16x8*)(A1 + (size_t)arow * 128 + (kk - 4) * 32 + quad * 8);
      } else if (ADT == 0) {
        afr[kk] = *(const bf16x8*)((const uint16_t*)A0v + (size_t)arow * 128 + kk * 32 + quad * 8);
      } else {
        const float* p = (const float*)A0v + (size_t)arow * 128 + kk * 32 + quad * 8;
        f32x4 f0 = *(const f32x4*)p;
        f32x4 f1 = *(const f32x4*)(p + 4);
        bf16x8 a;
        a[0] = (short)f2bf(f0[0]); a[1] = (short)f2bf(f0[1]);
        a[2] = (short)f2bf(f0[2]); a[3] = (short)f2bf(f0[3]);
        a[4] = (short)f2bf(f1[0]); a[5] = (short)f2bf(f1[1]);
        a[6] = (short)f2bf(f1[2]); a[7] = (short)f2bf(f1[3]);
        afr[kk] = a;
      }
    }
#pragma unroll
    for (int nt = 0; nt < NT; nt++) {
      f32x4 acc = {0.f, 0.f, 0.f, 0.f};
#pragma unroll
      for (int kk = 0; kk < KT; kk++) {
        bf16x8 b = *(const bf16x8*)(&lds[((nt * KT + kk) * 64 + lane) * 8]);
        acc = __builtin_amdgcn_mfma_f32_16x16x32_bf16(afr[kk], b, acc, 0, 0, 0);
      }
      const int col = n0 + nt * 16 + m;
      const float bv = bias[col];
      float vals[4];
#pragma unroll
      for (int r = 0; r < 4; r++) {
        float v = acc[r] + bv;
        if (RELU) v = fmaxf(v, 0.f);
        vals[r] = v;
        size_t oidx = (size_t)(row0 + quad * 4 + r) * 128 + col;
        if (ODT == 0) ((uint16_t*)Dv)[oidx] = f2bf(v);
        else          ((float*)Dv)[oidx] = v;
      }
      if (STATS) {
        float s = vals[0] + vals[1] + vals[2] + vals[3];
        float q = vals[0]*vals[0] + vals[1]*vals[1] + vals[2]*vals[2] + vals[3]*vals[3];
        s += __shfl_xor(s, 16); s += __shfl_xor(s, 32);
        q += __shfl_xor(q, 16); q += __shfl_xor(q, 32);
        if (quad == 0) {
          atomicAdd(&s_sum[nt * 16 + m], s);
          atomicAdd(&s_sq [nt * 16 + m], q);
        }
      }
    }
  }
  if (STATS) {
    __syncthreads();
    if (tid < NC) {
      int slot = (blockIdx.x + blockIdx.y) & (NSHADOW - 1);
      atomicAdd(&shadow[slot * 256 +       n0 + tid], s_sum[tid]);
      atomicAdd(&shadow[slot * 256 + 128 + n0 + tid], s_sq [tid]);
    }
  }
}

// ---------- gather + max over S neighbors (internal bf16) ----------
template<int S>
__global__ __launch_bounds__(256) void gather_k(
    const uint32_t* __restrict__ H, const int* __restrict__ idx,
    uint32_t* __restrict__ OUT, int M)
{
  const int lane = threadIdx.x & 63;
  int w = blockIdx.x * 4 + (threadIdx.x >> 6);
  const int nw = gridDim.x * 4;
  for (int r = w; r < M; r += nw) {
    const int* ir = idx + (size_t)r * S;
    float m0 = -3.4e38f, m1 = -3.4e38f;
#pragma unroll
    for (int s = 0; s < S; s++) {
      uint32_t j = (uint32_t)ir[s];
      if (j >= (uint32_t)M) j = 0;          // safety clamp
      uint32_t v = H[(size_t)j * 64 + lane];
      m0 = fmaxf(m0, bflo(v));
      m1 = fmaxf(m1, bfhi(v));
    }
    OUT[(size_t)r * 64 + lane] = (__float_as_uint(m1) & 0xffff0000u) | (__float_as_uint(m0) >> 16);
  }
}

// ---------- BN (batch stats from shadow slots) + row L2 normalize ----------
__global__ __launch_bounds__(256) void bn_norm_k(
    const uint32_t* __restrict__ Y, const float* __restrict__ shadow,
    const float* __restrict__ fgb, uint32_t* __restrict__ X, int M)
{
  __shared__ float sc[128], sh[128];
  const int tid = threadIdx.x;
  if (tid < 128) {
    float s = 0.f, q = 0.f;
    for (int sl = 0; sl < NSHADOW; sl++) {
      s += shadow[sl * 256 + tid];
      q += shadow[sl * 256 + 128 + tid];
    }
    float invN = 1.0f / (float)M;
    float mean = s * invN;
    float var  = fmaxf(q * invN - mean * mean, 0.f);
    float g = fgb[tid] * rsqrtf(var + 1e-5f);
    sc[tid] = g;
    sh[tid] = fgb[128 + tid] - mean * g;
  }
  __syncthreads();
  const int lane = tid & 63;
  const float s0 = sc[2*lane], s1 = sc[2*lane+1];
  const float h0 = sh[2*lane], h1 = sh[2*lane+1];
  int w = blockIdx.x * 4 + (tid >> 6);
  const int nw = gridDim.x * 4;
  for (int r = w; r < M; r += nw) {
    uint32_t v = Y[(size_t)r * 64 + lane];
    float x0 = bflo(v) * s0 + h0;
    float x1 = bfhi(v) * s1 + h1;
    float q = x0*x0 + x1*x1;
    q += __shfl_xor(q, 1);  q += __shfl_xor(q, 2);  q += __shfl_xor(q, 4);
    q += __shfl_xor(q, 8);  q += __shfl_xor(q, 16); q += __shfl_xor(q, 32);
    float inv = 1.0f / (sqrtf(q) + 1e-6f);
    x0 *= inv; x1 *= inv;
    X[(size_t)r * 64 + lane] = ((uint32_t)f2bf(x1) << 16) | (uint32_t)f2bf(x0);
  }
}

// ---------- launch ----------
extern "C" void kernel_launch(void* const* d_in, const int* in_sizes, int n_in,
                              void* d_out, int out_size, void* d_ws, size_t ws_size,
                              hipStream_t stream)
{
  const float* features = (const float*)d_in[0];
  const int*   idx1     = (const int*)d_in[1];
  const int*   idx2     = (const int*)d_in[2];
  const float* agg1_W   = (const float*)d_in[3];
  const float* agg1_b   = (const float*)d_in[4];
  const float* fc1_W    = (const float*)d_in[5];
  const float* fc1_b    = (const float*)d_in[6];
  const float* agg2_W   = (const float*)d_in[7];
  const float* agg2_b   = (const float*)d_in[8];
  const float* fc2_W    = (const float*)d_in[9];
  const float* fc2_b    = (const float*)d_in[10];
  const float* bn_g     = (const float*)d_in[11];
  const float* bn_b     = (const float*)d_in[12];

  const int N = in_sizes[0] / 128;          // 50000 (multiple of 16)

  // workspace carve-up (16B-aligned); ~25.8 MB
  char* w = (char*)d_ws;
  float* shadow = (float*)w; w += NSHADOW * 256 * 4;   // BN stats shadow slots
  uint16_t* T1  = (uint16_t*)w; w += 128 * 128 * 2;
  uint16_t* Tf1 = (uint16_t*)w; w += 128 * 256 * 2;
  uint16_t* T2  = (uint16_t*)w; w += 128 * 128 * 2;
  uint16_t* Tf2 = (uint16_t*)w; w += 128 * 256 * 2;
  float* fb  = (float*)w; w += 512 * 4;     // [b1|bf1|b2|bf2] f32
  float* fgb = (float*)w; w += 256 * 4;     // [gamma|beta] f32
  size_t NB = (size_t)N * 128 * 2;
  uint16_t* bufA = (uint16_t*)w; w += NB;   // agg1 -> x
  uint16_t* bufB = (uint16_t*)w; w += NB;   // y -> agg2
  uint16_t* hbuf = (uint16_t*)d_out;        // h1/h2 scratch lives in d_out (25.6 MB >= 12.8)

  prep_k<<<384, 256, 0, stream>>>(agg1_W, fc1_W, agg2_W, fc2_W,
      agg1_b, fc1_b, agg2_b, fc2_b, bn_g, bn_b, T1, Tf1, T2, Tf2, fb, fgb, shadow);

  const int rb = (N + 63) / 64;             // 782

  // h1 = relu(X @ W1 + b1) -> d_out scratch (bf16)
  gemm_k<128, 2, true, false, 1, 0><<<dim3(rb, 4), 256, 0, stream>>>(
      features, nullptr, T1, fb + 0, hbuf, nullptr, N);
  // agg1 = max-gather(h1, idx1) -> bufA
  gather_k<25><<<2048, 256, 0, stream>>>((const uint32_t*)hbuf, idx1, (uint32_t*)bufA, N);
  // y = relu([X, agg1] @ fc1 + b) -> bufB, fused BN stats (shadow slots)
  gemm_k<256, 2, true, true, 1, 0><<<dim3(rb, 4), 256, 0, stream>>>(
      features, bufA, Tf1, fb + 128, bufB, shadow, N);
  // x = L2normalize(BN(y)) -> bufA
  bn_norm_k<<<512, 256, 0, stream>>>((const uint32_t*)bufB, shadow, fgb,
                                     (uint32_t*)bufA, N);
  // h2 = relu(x @ W2 + b2) -> d_out scratch
  gemm_k<128, 2, true, false, 0, 0><<<dim3(rb, 4), 256, 0, stream>>>(
      bufA, nullptr, T2, fb + 256, hbuf, nullptr, N);
  // agg2 = max-gather(h2, idx2) -> bufB
  gather_k<25><<<2048, 256, 0, stream>>>((const uint32_t*)hbuf, idx2, (uint32_t*)bufB, N);
  // out = [x, agg2] @ fc2 + b -> d_out (f32)
  gemm_k<256, 2, false, false, 0, 1><<<dim3(rb, 4), 256, 0, stream>>>(
      bufA, bufB, Tf2, fb + 384, d_out, nullptr, N);

  (void)n_in; (void)out_size; (void)ws_size;
}